// Round 3
// baseline (26.282 us; speedup 1.0000x reference)
//
#include <hip/hip_runtime.h>

// RerankLoss: margin-ranking hinge over all pos-neg pairs per row.
// scores: [B, L] f32, labels: [B, L] i32 in {0,1}; output: scalar f32.
// out = (1/B) * sum_b [ sum_{i pos, j neg} relu(1 - (s_i - s_j)) / (n_pos*n_neg) ]
//
// Single fused kernel: 4 waves/block, one wave per sample. Ballot-compact
// pos/neg into per-wave LDS, pair-sweep negatives via float4 LDS broadcast,
// wave-reduce, block-reduce, one atomicAdd(d_out) per block. d_out is zeroed
// by a 4-byte hipMemsetAsync (graph-capturable) before the kernel.

constexpr int L  = 200;
constexpr int LQ = L / 4;           // 50 quads per row
constexpr float MARGIN = 1.0f;

__global__ __launch_bounds__(256) void rerank_fused(
    const float* __restrict__ scores,
    const int*   __restrict__ labels,
    float*       __restrict__ out,
    float invB)
{
    __shared__ __align__(16) float posv[4][208];
    __shared__ __align__(16) float negv[4][208];
    __shared__ float wpart[4];

    const int tid  = threadIdx.x;
    const int w    = tid >> 6;       // wave id 0..3
    const int lane = tid & 63;
    const int b    = blockIdx.x * 4 + w;   // sample for this wave

    // --- coalesced vector load: lanes 0..49 hold 4 consecutive elements ---
    float4 sv = make_float4(0.f, 0.f, 0.f, 0.f);
    int4   lv = make_int4(0, 0, 0, 0);
    const bool act = lane < LQ;
    if (act) {
        sv = ((const float4*)(scores + (long)b * L))[lane];
        lv = ((const int4*)(labels + (long)b * L))[lane];
    }
    const float ev[4] = {sv.x, sv.y, sv.z, sv.w};
    const int   lb[4] = {lv.x, lv.y, lv.z, lv.w};

    // --- ballot compaction: unique LDS slot = base + popc(mask & lower) ---
    const unsigned long long lower = (1ull << lane) - 1ull;
    int npos = 0, nneg = 0;
#pragma unroll
    for (int j = 0; j < 4; ++j) {
        const bool isp = act && (lb[j] != 0);
        const bool isn = act && (lb[j] == 0);
        const unsigned long long mp = __ballot(isp);
        const unsigned long long mn = __ballot(isn);
        if (isp) posv[w][npos + __popcll(mp & lower)] = ev[j];
        if (isn) negv[w][nneg + __popcll(mn & lower)] = ev[j];
        npos += __popcll(mp);      // wave-uniform
        nneg += __popcll(mn);
    }

    // pad negatives to a multiple of 4; relu(c - 3e38) == 0 kills pad terms
    const int nneg4 = (nneg + 3) & ~3;
    if (lane < nneg4 - nneg) negv[w][nneg + lane] = -3.0e38f;
    __syncthreads();               // drain LDS writes (and align the 4 waves)

    // --- pair loop: lane owns positive i; negatives via LDS broadcast ---
    float acc = 0.0f;
    const float4* nv = (const float4*)&negv[w][0];
    const int nq = nneg4 >> 2;
    for (int i = lane; i < npos; i += 64) {
        const float c = MARGIN - posv[w][i];
        float a0 = 0.f, a1 = 0.f, a2 = 0.f, a3 = 0.f;
        for (int j = 0; j < nq; ++j) {
            float4 n = nv[j];
            a0 += fmaxf(c + n.x, 0.0f);
            a1 += fmaxf(c + n.y, 0.0f);
            a2 += fmaxf(c + n.z, 0.0f);
            a3 += fmaxf(c + n.w, 0.0f);
        }
        acc += (a0 + a1) + (a2 + a3);
    }

    // wave64 reduce
    for (int o = 32; o; o >>= 1) acc += __shfl_down(acc, o, 64);
    if (lane == 0) {
        const float np = (float)npos * (float)nneg;
        wpart[w] = (np > 0.0f) ? (acc / np) * invB : 0.0f;
    }
    __syncthreads();
    if (tid == 0) {
        const float s = (wpart[0] + wpart[1]) + (wpart[2] + wpart[3]);
        atomicAdd(out, s);
    }
}

extern "C" void kernel_launch(void* const* d_in, const int* in_sizes, int n_in,
                              void* d_out, int out_size, void* d_ws, size_t ws_size,
                              hipStream_t stream)
{
    const float* scores = (const float*)d_in[0];
    const int*   labels = (const int*)d_in[1];
    float*       out    = (float*)d_out;

    const int B = in_sizes[0] / L;

    hipMemsetAsync(out, 0, sizeof(float), stream);
    rerank_fused<<<B / 4, 256, 0, stream>>>(scores, labels, out, 1.0f / (float)B);
}